// Round 2
// baseline (768.846 us; speedup 1.0000x reference)
//
#include <hip/hip_runtime.h>
#include <hip/hip_bf16.h>
#include <stdint.h>

typedef _Float16 half8 __attribute__((ext_vector_type(8)));
typedef _Float16 half4 __attribute__((ext_vector_type(4)));
typedef float    f32x4 __attribute__((ext_vector_type(4)));

#define MFMA16(a, b, c) __builtin_amdgcn_mfma_f32_16x16x32_f16(a, b, c, 0, 0, 0)

// ---------------------------------------------------------------------------
// Generic fp32->fp16 transpose: X [R][C] fp32 -> Y [C][R] fp16, z-batched.
// R, C multiples of 32.
// ---------------------------------------------------------------------------
__global__ __launch_bounds__(256) void transpose_to_f16(
    const float* __restrict__ X, _Float16* __restrict__ Y,
    int R, int C, long inBS, long outBS)
{
    __shared__ float t[32][33];
    const int bz = blockIdx.z;
    X += (long)bz * inBS;
    Y += (long)bz * outBS;
    const int c0 = blockIdx.x * 32, r0 = blockIdx.y * 32;
    const int tx = threadIdx.x & 31, ty = threadIdx.x >> 5;  // ty 0..7
    for (int i = 0; i < 4; ++i)
        t[ty + i * 8][tx] = X[(long)(r0 + ty + i * 8) * C + c0 + tx];
    __syncthreads();
    for (int i = 0; i < 4; ++i)
        Y[(long)(c0 + ty + i * 8) * R + r0 + tx] = (_Float16)t[tx][ty + i * 8];
}

// ---------------------------------------------------------------------------
// MFMA GEMM: C[M,N] = A[M,K](fp32,row-major,lda) @ B, with B given as
// BT[N,K] fp16 (ldbt), optional bias[N], output fp16 or fp32 (ldc).
// Block tile 128x128xK(step 64); 256 threads = 4 waves, wave tile 32x128.
// M % 128 == 0, K % 64 == 0. N may be < 128 (bounds-checked stores).
//
// __launch_bounds__(256, 2): 2 waves/EU -> 256 unified VGPR/wave budget.
// Without it the compiler spilled the 64-reg accumulator array to scratch
// (R1 evidence: WRITE_SIZE 264 MB == 256 B/thread * 16 K-iters of spill).
// ---------------------------------------------------------------------------
__global__ __launch_bounds__(256, 2) void gemm_f16(
    const float* __restrict__ A, const _Float16* __restrict__ BT,
    const float* __restrict__ bias, void* __restrict__ Cout,
    int M, int N, int K, int lda, int ldbt, int ldc,
    long aBS, long bBS, long cBS, int c_half)
{
    // +8 halves pad: keeps 16B row alignment (144 B stride) and avoids the
    // bank pile-up a 128 B stride would cause on frag reads.
    __shared__ __align__(16) _Float16 As[128][72];
    __shared__ __align__(16) _Float16 Bs[128][72];

    const int bz = blockIdx.z;
    A  += (long)bz * aBS;
    BT += (long)bz * bBS;

    const int n0 = blockIdx.x * 128;
    const int m0 = blockIdx.y * 128;
    const int tid  = threadIdx.x;
    const int wave = tid >> 6, lane = tid & 63;
    const int m16  = lane & 15, quad = lane >> 4;

    f32x4 acc[2][8];
    {
        f32x4 z = {0.f, 0.f, 0.f, 0.f};
        for (int i = 0; i < 2; ++i)
            for (int j = 0; j < 8; ++j) acc[i][j] = z;
    }

    for (int k0 = 0; k0 < K; k0 += 64) {
        // ---- stage A tile: 128 rows x 64 cols fp32 -> fp16
        {
            const int cc = (tid & 15) * 4;
            const int rb = tid >> 4;
            for (int p = 0; p < 8; ++p) {
                const int r = rb + p * 16;
                const float4 v = *(const float4*)(A + (long)(m0 + r) * lda + k0 + cc);
                half4 hv;
                hv[0] = (_Float16)v.x; hv[1] = (_Float16)v.y;
                hv[2] = (_Float16)v.z; hv[3] = (_Float16)v.w;
                *(half4*)&As[r][cc] = hv;
            }
        }
        // ---- stage B tile: 128 rows (n) x 64 cols (k) fp16, already [n][k]
        {
            const int j  = tid >> 1;
            const int cc = (tid & 1) * 32;
            int jn = n0 + j; if (jn > N - 1) jn = N - 1;  // clamp for N<128
            const _Float16* bp = BT + (long)jn * ldbt + k0 + cc;
            *(half8*)&Bs[j][cc]      = *(const half8*)(bp);
            *(half8*)&Bs[j][cc + 8]  = *(const half8*)(bp + 8);
            *(half8*)&Bs[j][cc + 16] = *(const half8*)(bp + 16);
            *(half8*)&Bs[j][cc + 24] = *(const half8*)(bp + 24);
        }
        __syncthreads();
        for (int ks = 0; ks < 2; ++ks) {
            const int ko = ks * 32 + quad * 8;
            const half8 a0 = *(const half8*)&As[wave * 32 + m16][ko];
            const half8 a1 = *(const half8*)&As[wave * 32 + 16 + m16][ko];
            for (int c = 0; c < 8; ++c) {
                const half8 bf = *(const half8*)&Bs[c * 16 + m16][ko];
                acc[0][c] = MFMA16(a0, bf, acc[0][c]);
                acc[1][c] = MFMA16(a1, bf, acc[1][c]);
            }
        }
        __syncthreads();
    }

    // ---- epilogue: C/D layout col=lane&15, row=quad*4+r
    for (int hh = 0; hh < 2; ++hh) {
        for (int c = 0; c < 8; ++c) {
            const int col = n0 + c * 16 + m16;
            if (col >= N) continue;
            const float bb = bias ? bias[col] : 0.f;
            for (int r = 0; r < 4; ++r) {
                const int row = m0 + wave * 32 + hh * 16 + quad * 4 + r;
                const float v = acc[hh][c][r] + bb;
                if (c_half)
                    ((_Float16*)Cout)[(long)bz * cBS + (long)row * ldc + col] = (_Float16)v;
                else
                    ((float*)Cout)[(long)bz * cBS + (long)row * ldc + col] = v;
            }
        }
    }
}

// ---------------------------------------------------------------------------
// Pass 1: per (b,h,s) row stats m = max_t score, l = sum exp(score-m),
// causal. Scores via MFMA from q_all/k_all fp16 [B*S][H*HS]. One block =
// 64 query rows (4 waves x 16), loops over 16-col k tiles.
// ---------------------------------------------------------------------------
__global__ __launch_bounds__(256) void attn_stats(
    const _Float16* __restrict__ q_all, const _Float16* __restrict__ k_all,
    float* __restrict__ m_out, float* __restrict__ il_out)
{
    const int st = blockIdx.x, h = blockIdx.y, b = blockIdx.z;
    const int tid = threadIdx.x, wave = tid >> 6, lane = tid & 63;
    const int m16 = lane & 15, quad = lane >> 4;
    const int s0 = st * 64 + wave * 16;

    const _Float16* qp = q_all + ((long)(b * 1024 + s0 + m16)) * 1024 + h * 64 + quad * 8;
    const half8 a0 = *(const half8*)qp;
    const half8 a1 = *(const half8*)(qp + 32);

    float mr[4], lr[4];
    for (int r = 0; r < 4; ++r) { mr[r] = -3.0e38f; lr[r] = 0.f; }

    const int ntiles = st * 4 + 4;  // covers cols 0 .. st*64+63
    const _Float16* kb = k_all + ((long)(b * 1024 + m16)) * 1024 + h * 64 + quad * 8;
    for (int tt = 0; tt < ntiles; ++tt) {
        const _Float16* kp = kb + (long)tt * 16 * 1024;
        const half8 b0 = *(const half8*)kp;
        const half8 b1 = *(const half8*)(kp + 32);
        f32x4 c = {0.f, 0.f, 0.f, 0.f};
        c = MFMA16(a0, b0, c);
        c = MFMA16(a1, b1, c);
        const int col = tt * 16 + m16;
        for (int r = 0; r < 4; ++r) {
            const int row = s0 + quad * 4 + r;
            if (col <= row) {
                const float z  = c[r] * 0.125f;      // 1/sqrt(64)
                const float nm = fmaxf(mr[r], z);
                lr[r] = lr[r] * __expf(mr[r] - nm) + __expf(z - nm);
                mr[r] = nm;
            }
        }
    }
    // merge across the 16 lanes sharing each row (same quad)
    for (int mk = 1; mk < 16; mk <<= 1) {
        for (int r = 0; r < 4; ++r) {
            const float om = __shfl_xor(mr[r], mk);
            const float ol = __shfl_xor(lr[r], mk);
            const float nm = fmaxf(mr[r], om);
            lr[r] = lr[r] * __expf(mr[r] - nm) + ol * __expf(om - nm);
            mr[r] = nm;
        }
    }
    if (m16 == 0) {
        for (int r = 0; r < 4; ++r) {
            const long idx = ((long)(b * 16 + h)) * 1024 + s0 + quad * 4 + r;
            m_out[idx]  = mr[r];
            il_out[idx] = 1.f / lr[r];
        }
    }
}

// ---------------------------------------------------------------------------
// Pass 2: attn_mean[b,s,t] = (1/H) sum_h exp(score-m)*invl. One block owns a
// 64x64 (s,t) output tile and loops all 16 heads, accumulating in registers —
// single fp32 write, no atomics. Upper-triangle tiles write zeros (replaces
// the 16.8 MB memset pass).
// ---------------------------------------------------------------------------
__global__ __launch_bounds__(256) void attn_pmean(
    const _Float16* __restrict__ q_all, const _Float16* __restrict__ k_all,
    const float* __restrict__ m_in, const float* __restrict__ il_in,
    float* __restrict__ attn)
{
    const int ttile = blockIdx.x, stile = blockIdx.y, b = blockIdx.z;
    const int tid = threadIdx.x;
    if (ttile > stile) {
        // strictly-upper tile: zero-fill (harness poisons d_out each call)
        const int row = ttile * 0 + stile * 64 + (tid >> 4);  // 16 rows per pass
        const int c4  = (tid & 15) * 4;
        float4 z = {0.f, 0.f, 0.f, 0.f};
        for (int i = 0; i < 4; ++i) {
            const int r = stile * 64 + (tid >> 4) + i * 16;
            (void)row;
            *(float4*)&attn[((long)(b * 1024 + r)) * 1024 + ttile * 64 + c4] = z;
        }
        return;
    }
    const int wave = tid >> 6, lane = tid & 63;
    const int m16 = lane & 15, quad = lane >> 4;
    const int s0 = stile * 64 + wave * 16;
    const int t0 = ttile * 64;

    float pm[4][4];
    for (int c = 0; c < 4; ++c)
        for (int r = 0; r < 4; ++r) pm[c][r] = 0.f;

    for (int h = 0; h < 16; ++h) {
        const _Float16* qp = q_all + ((long)(b * 1024 + s0 + m16)) * 1024 + h * 64 + quad * 8;
        const half8 a0 = *(const half8*)qp;
        const half8 a1 = *(const half8*)(qp + 32);
        float mrow[4], irow[4];
        for (int r = 0; r < 4; ++r) {
            const long idx = ((long)(b * 16 + h)) * 1024 + s0 + quad * 4 + r;
            mrow[r] = m_in[idx];
            irow[r] = il_in[idx];
        }
        for (int c = 0; c < 4; ++c) {
            const _Float16* kp = k_all + ((long)(b * 1024 + t0 + c * 16 + m16)) * 1024 + h * 64 + quad * 8;
            const half8 b0 = *(const half8*)kp;
            const half8 b1 = *(const half8*)(kp + 32);
            f32x4 cc = {0.f, 0.f, 0.f, 0.f};
            cc = MFMA16(a0, b0, cc);
            cc = MFMA16(a1, b1, cc);
            const int col = t0 + c * 16 + m16;
            for (int r = 0; r < 4; ++r) {
                const int row = s0 + quad * 4 + r;
                if (col <= row)
                    pm[c][r] += __expf(cc[r] * 0.125f - mrow[r]) * irow[r];
            }
        }
    }
    for (int c = 0; c < 4; ++c) {
        for (int r = 0; r < 4; ++r) {
            const int row = s0 + quad * 4 + r;
            const int col = t0 + c * 16 + m16;
            attn[((long)(b * 1024 + row)) * 1024 + col] = pm[c][r] * 0.0625f;  // 1/H
        }
    }
}

// ---------------------------------------------------------------------------
extern "C" void kernel_launch(void* const* d_in, const int* in_sizes, int n_in,
                              void* d_out, int out_size, void* d_ws, size_t ws_size,
                              hipStream_t stream)
{
    const float* queries = (const float*)d_in[0];   // [4,1024,1024]
    const float* keys    = (const float*)d_in[1];
    const float* values  = (const float*)d_in[2];
    // d_in[3] = tril mask: causality hardcoded
    const float* Wq = (const float*)d_in[4];        // [16,1024,64]
    const float* bq = (const float*)d_in[5];        // [16,64] == bias[n]
    const float* Wk = (const float*)d_in[6];
    const float* bk = (const float*)d_in[7];
    const float* Wv = (const float*)d_in[8];        // [1024,64]
    const float* bv = (const float*)d_in[9];        // [64]
    const float* Wo = (const float*)d_in[10];       // [64,1024]
    const float* bo = (const float*)d_in[11];       // [1024]

    float* out_ptr  = (float*)d_out;                   // [4096][1024]
    float* attn_ptr = out_ptr + (long)4096 * 1024;     // [4][1024][1024]

    uint8_t* w = (uint8_t*)d_ws;
    size_t off = 0;
    auto alloc = [&](size_t bytes) {
        void* p = w + off;
        off = (off + bytes + 255) & ~(size_t)255;
        return p;
    };
    _Float16* WqT  = (_Float16*)alloc((size_t)1024 * 1024 * 2);  // [n=h*64+e][d]
    _Float16* WkT  = (_Float16*)alloc((size_t)1024 * 1024 * 2);
    _Float16* WvT  = (_Float16*)alloc((size_t)64 * 1024 * 2);    // [e][d]
    _Float16* WoT  = (_Float16*)alloc((size_t)1024 * 64 * 2);    // [d][e]
    _Float16* qall = (_Float16*)alloc((size_t)4096 * 1024 * 2);  // fp16 [B*S][H*HS]
    _Float16* kall = (_Float16*)alloc((size_t)4096 * 1024 * 2);
    float*    vbuf = (float*)alloc((size_t)4096 * 64 * 4);       // [B*S][64] fp32
    _Float16* vT   = (_Float16*)alloc((size_t)4 * 64 * 1024 * 2);// per-b [e][t]
    float*    ctx  = (float*)alloc((size_t)4096 * 64 * 4);
    float*    mbuf = (float*)alloc((size_t)65536 * 4);           // [B,H,S]
    float*    ilbuf= (float*)alloc((size_t)65536 * 4);
    (void)ws_size; (void)in_sizes; (void)n_in; (void)out_size;

    // weight transposes/conversions
    transpose_to_f16<<<dim3(2, 32, 16), 256, 0, stream>>>(Wq, WqT, 1024, 64, 65536, 65536);
    transpose_to_f16<<<dim3(2, 32, 16), 256, 0, stream>>>(Wk, WkT, 1024, 64, 65536, 65536);
    transpose_to_f16<<<dim3(2, 32, 1),  256, 0, stream>>>(Wv, WvT, 1024, 64, 0, 0);
    transpose_to_f16<<<dim3(32, 2, 1),  256, 0, stream>>>(Wo, WoT, 64, 1024, 0, 0);

    // projections: q_all/k_all fp16, v fp32
    gemm_f16<<<dim3(8, 32, 1), 256, 0, stream>>>(queries, WqT, bq, qall,
        4096, 1024, 1024, 1024, 1024, 1024, 0, 0, 0, 1);
    gemm_f16<<<dim3(8, 32, 1), 256, 0, stream>>>(keys, WkT, bk, kall,
        4096, 1024, 1024, 1024, 1024, 1024, 0, 0, 0, 1);
    gemm_f16<<<dim3(1, 32, 1), 256, 0, stream>>>(values, WvT, bv, vbuf,
        4096, 64, 1024, 1024, 1024, 64, 0, 0, 0, 0);

    // vT per batch: [1024][64] -> [64][1024] fp16
    transpose_to_f16<<<dim3(2, 32, 4), 256, 0, stream>>>(vbuf, vT, 1024, 64, 65536, 65536);

    // softmax stats then head-averaged probabilities (writes full attn incl. zeros)
    attn_stats<<<dim3(16, 16, 4), 256, 0, stream>>>(qall, kall, mbuf, ilbuf);
    attn_pmean<<<dim3(16, 16, 4), 256, 0, stream>>>(qall, kall, mbuf, ilbuf, attn_ptr);

    // ctx[b] = attn_mean[b] @ v[b]   (A fp32 read back from d_out)
    gemm_f16<<<dim3(1, 8, 4), 256, 0, stream>>>(attn_ptr, vT, nullptr, ctx,
        1024, 64, 1024, 1024, 1024, 64,
        (long)1024 * 1024, (long)64 * 1024, (long)1024 * 64, 0);
    // out = ctx @ Wo + bo
    gemm_f16<<<dim3(8, 32, 1), 256, 0, stream>>>(ctx, WoT, bo, out_ptr,
        4096, 1024, 64, 64, 64, 1024, 0, 0, 0, 0);
}

// Round 5
// 577.469 us; speedup vs baseline: 1.3314x; 1.3314x over previous
//
#include <hip/hip_runtime.h>
#include <hip/hip_bf16.h>
#include <stdint.h>

typedef _Float16 half8 __attribute__((ext_vector_type(8)));
typedef _Float16 half4 __attribute__((ext_vector_type(4)));
typedef float    f32x4 __attribute__((ext_vector_type(4)));

#define MFMA16(a, b, c) __builtin_amdgcn_mfma_f32_16x16x32_f16(a, b, c, 0, 0, 0)

// ---------------------------------------------------------------------------
// Generic fp32->fp16 transpose: X [R][C] fp32 -> Y [C][R] fp16, z-batched.
// R, C multiples of 32.
// ---------------------------------------------------------------------------
__global__ __launch_bounds__(256) void transpose_to_f16(
    const float* __restrict__ X, _Float16* __restrict__ Y,
    int R, int C, long inBS, long outBS)
{
    __shared__ float t[32][33];
    const int bz = blockIdx.z;
    X += (long)bz * inBS;
    Y += (long)bz * outBS;
    const int c0 = blockIdx.x * 32, r0 = blockIdx.y * 32;
    const int tx = threadIdx.x & 31, ty = threadIdx.x >> 5;  // ty 0..7
#pragma unroll
    for (int i = 0; i < 4; ++i)
        t[ty + i * 8][tx] = X[(long)(r0 + ty + i * 8) * C + c0 + tx];
    __syncthreads();
#pragma unroll
    for (int i = 0; i < 4; ++i)
        Y[(long)(c0 + ty + i * 8) * R + r0 + tx] = (_Float16)t[tx][ty + i * 8];
}

// ---------------------------------------------------------------------------
// MFMA GEMM: C[M,N] = A[M,K](fp32,row-major,lda) @ B, with B given as
// BT[N,K] fp16 (ldbt), optional bias[N], output fp16 or fp32 (ldc).
// Block tile 128x128xK(step 64); 256 threads = 4 waves, wave tile 32x128.
// M % 128 == 0, K % 64 == 0. N may be < 128 (bounds-checked stores).
//
// R2 lesson: every loop that indexes acc[][] MUST be fully unrolled —
// otherwise acc becomes a dynamically-indexed local array and lives in
// scratch (R1/R2 evidence: WRITE_SIZE ~250 MB == 256 B/thread/K-iter of
// scratch traffic, VGPR_Count 52-80). #pragma unroll everywhere.
// ---------------------------------------------------------------------------
__global__ __launch_bounds__(256, 2) void gemm_f16(
    const float* __restrict__ A, const _Float16* __restrict__ BT,
    const float* __restrict__ bias, void* __restrict__ Cout,
    int M, int N, int K, int lda, int ldbt, int ldc,
    long aBS, long bBS, long cBS, int c_half)
{
    // +8 halves pad: keeps 16B row alignment (144 B stride) and avoids the
    // bank pile-up a 128 B stride would cause on frag reads.
    __shared__ __align__(16) _Float16 As[128][72];
    __shared__ __align__(16) _Float16 Bs[128][72];

    const int bz = blockIdx.z;
    A  += (long)bz * aBS;
    BT += (long)bz * bBS;

    const int n0 = blockIdx.x * 128;
    const int m0 = blockIdx.y * 128;
    const int tid  = threadIdx.x;
    const int wave = tid >> 6, lane = tid & 63;
    const int m16  = lane & 15, quad = lane >> 4;

    f32x4 acc[2][8];
    {
        f32x4 z = {0.f, 0.f, 0.f, 0.f};
#pragma unroll
        for (int i = 0; i < 2; ++i)
#pragma unroll
            for (int j = 0; j < 8; ++j) acc[i][j] = z;
    }

    for (int k0 = 0; k0 < K; k0 += 64) {
        // ---- stage A tile: 128 rows x 64 cols fp32 -> fp16
        {
            const int cc = (tid & 15) * 4;
            const int rb = tid >> 4;
#pragma unroll
            for (int p = 0; p < 8; ++p) {
                const int r = rb + p * 16;
                const float4 v = *(const float4*)(A + (long)(m0 + r) * lda + k0 + cc);
                half4 hv;
                hv[0] = (_Float16)v.x; hv[1] = (_Float16)v.y;
                hv[2] = (_Float16)v.z; hv[3] = (_Float16)v.w;
                *(half4*)&As[r][cc] = hv;
            }
        }
        // ---- stage B tile: 128 rows (n) x 64 cols (k) fp16, already [n][k]
        {
            const int j  = tid >> 1;
            const int cc = (tid & 1) * 32;
            int jn = n0 + j; if (jn > N - 1) jn = N - 1;  // clamp for N<128
            const _Float16* bp = BT + (long)jn * ldbt + k0 + cc;
            *(half8*)&Bs[j][cc]      = *(const half8*)(bp);
            *(half8*)&Bs[j][cc + 8]  = *(const half8*)(bp + 8);
            *(half8*)&Bs[j][cc + 16] = *(const half8*)(bp + 16);
            *(half8*)&Bs[j][cc + 24] = *(const half8*)(bp + 24);
        }
        __syncthreads();
#pragma unroll
        for (int ks = 0; ks < 2; ++ks) {
            const int ko = ks * 32 + quad * 8;
            const half8 a0 = *(const half8*)&As[wave * 32 + m16][ko];
            const half8 a1 = *(const half8*)&As[wave * 32 + 16 + m16][ko];
#pragma unroll
            for (int c = 0; c < 8; ++c) {
                const half8 bf = *(const half8*)&Bs[c * 16 + m16][ko];
                acc[0][c] = MFMA16(a0, bf, acc[0][c]);
                acc[1][c] = MFMA16(a1, bf, acc[1][c]);
            }
        }
        __syncthreads();
    }

    // ---- epilogue: C/D layout col=lane&15, row=quad*4+r
#pragma unroll
    for (int hh = 0; hh < 2; ++hh) {
#pragma unroll
        for (int c = 0; c < 8; ++c) {
            const int col = n0 + c * 16 + m16;
            if (col >= N) continue;
            const float bb = bias ? bias[col] : 0.f;
#pragma unroll
            for (int r = 0; r < 4; ++r) {
                const int row = m0 + wave * 32 + hh * 16 + quad * 4 + r;
                const float v = acc[hh][c][r] + bb;
                if (c_half)
                    ((_Float16*)Cout)[(long)bz * cBS + (long)row * ldc + col] = (_Float16)v;
                else
                    ((float*)Cout)[(long)bz * cBS + (long)row * ldc + col] = v;
            }
        }
    }
}

// ---------------------------------------------------------------------------
// Pass 1: per (b,h,s) row stats m = max_t score, l = sum exp(score-m),
// causal. Scores via MFMA from q_all/k_all fp16 [B*S][H*HS]. One block =
// 64 query rows (4 waves x 16), loops over 16-col k tiles.
// ---------------------------------------------------------------------------
__global__ __launch_bounds__(256) void attn_stats(
    const _Float16* __restrict__ q_all, const _Float16* __restrict__ k_all,
    float* __restrict__ m_out, float* __restrict__ il_out)
{
    const int st = blockIdx.x, h = blockIdx.y, b = blockIdx.z;
    const int tid = threadIdx.x, wave = tid >> 6, lane = tid & 63;
    const int m16 = lane & 15, quad = lane >> 4;
    const int s0 = st * 64 + wave * 16;

    const _Float16* qp = q_all + ((long)(b * 1024 + s0 + m16)) * 1024 + h * 64 + quad * 8;
    const half8 a0 = *(const half8*)qp;
    const half8 a1 = *(const half8*)(qp + 32);

    float mr[4], lr[4];
#pragma unroll
    for (int r = 0; r < 4; ++r) { mr[r] = -3.0e38f; lr[r] = 0.f; }

    const int ntiles = st * 4 + 4;  // covers cols 0 .. st*64+63
    const _Float16* kb = k_all + ((long)(b * 1024 + m16)) * 1024 + h * 64 + quad * 8;
    for (int tt = 0; tt < ntiles; ++tt) {
        const _Float16* kp = kb + (long)tt * 16 * 1024;
        const half8 b0 = *(const half8*)kp;
        const half8 b1 = *(const half8*)(kp + 32);
        f32x4 c = {0.f, 0.f, 0.f, 0.f};
        c = MFMA16(a0, b0, c);
        c = MFMA16(a1, b1, c);
        const int col = tt * 16 + m16;
#pragma unroll
        for (int r = 0; r < 4; ++r) {
            const int row = s0 + quad * 4 + r;
            if (col <= row) {
                const float z  = c[r] * 0.125f;      // 1/sqrt(64)
                const float nm = fmaxf(mr[r], z);
                lr[r] = lr[r] * __expf(mr[r] - nm) + __expf(z - nm);
                mr[r] = nm;
            }
        }
    }
    // merge across the 16 lanes sharing each row (same quad)
#pragma unroll
    for (int mk = 1; mk < 16; mk <<= 1) {
#pragma unroll
        for (int r = 0; r < 4; ++r) {
            const float om = __shfl_xor(mr[r], mk);
            const float ol = __shfl_xor(lr[r], mk);
            const float nm = fmaxf(mr[r], om);
            lr[r] = lr[r] * __expf(mr[r] - nm) + ol * __expf(om - nm);
            mr[r] = nm;
        }
    }
    if (m16 == 0) {
#pragma unroll
        for (int r = 0; r < 4; ++r) {
            const long idx = ((long)(b * 16 + h)) * 1024 + s0 + quad * 4 + r;
            m_out[idx]  = mr[r];
            il_out[idx] = 1.f / lr[r];
        }
    }
}

// ---------------------------------------------------------------------------
// Pass 2: attn_mean[b,s,t] = (1/H) sum_h exp(score-m)*invl. One block owns a
// 64x64 (s,t) output tile and loops all 16 heads, accumulating in registers —
// single fp32 write, no atomics. Upper-triangle tiles write zeros (replaces
// the 16.8 MB memset pass).
// ---------------------------------------------------------------------------
__global__ __launch_bounds__(256) void attn_pmean(
    const _Float16* __restrict__ q_all, const _Float16* __restrict__ k_all,
    const float* __restrict__ m_in, const float* __restrict__ il_in,
    float* __restrict__ attn)
{
    const int ttile = blockIdx.x, stile = blockIdx.y, b = blockIdx.z;
    const int tid = threadIdx.x;
    if (ttile > stile) {
        // strictly-upper tile: zero-fill (harness poisons d_out each call)
        const int c4 = (tid & 15) * 4;
        float4 z = {0.f, 0.f, 0.f, 0.f};
#pragma unroll
        for (int i = 0; i < 4; ++i) {
            const int r = stile * 64 + (tid >> 4) + i * 16;
            *(float4*)&attn[((long)(b * 1024 + r)) * 1024 + ttile * 64 + c4] = z;
        }
        return;
    }
    const int wave = tid >> 6, lane = tid & 63;
    const int m16 = lane & 15, quad = lane >> 4;
    const int s0 = stile * 64 + wave * 16;
    const int t0 = ttile * 64;

    float pm[4][4];
#pragma unroll
    for (int c = 0; c < 4; ++c)
#pragma unroll
        for (int r = 0; r < 4; ++r) pm[c][r] = 0.f;

    for (int h = 0; h < 16; ++h) {
        const _Float16* qp = q_all + ((long)(b * 1024 + s0 + m16)) * 1024 + h * 64 + quad * 8;
        const half8 a0 = *(const half8*)qp;
        const half8 a1 = *(const half8*)(qp + 32);
        float mrow[4], irow[4];
#pragma unroll
        for (int r = 0; r < 4; ++r) {
            const long idx = ((long)(b * 16 + h)) * 1024 + s0 + quad * 4 + r;
            mrow[r] = m_in[idx];
            irow[r] = il_in[idx];
        }
#pragma unroll
        for (int c = 0; c < 4; ++c) {
            const _Float16* kp = k_all + ((long)(b * 1024 + t0 + c * 16 + m16)) * 1024 + h * 64 + quad * 8;
            const half8 b0 = *(const half8*)kp;
            const half8 b1 = *(const half8*)(kp + 32);
            f32x4 cc = {0.f, 0.f, 0.f, 0.f};
            cc = MFMA16(a0, b0, cc);
            cc = MFMA16(a1, b1, cc);
            const int col = t0 + c * 16 + m16;
#pragma unroll
            for (int r = 0; r < 4; ++r) {
                const int row = s0 + quad * 4 + r;
                if (col <= row)
                    pm[c][r] += __expf(cc[r] * 0.125f - mrow[r]) * irow[r];
            }
        }
    }
#pragma unroll
    for (int c = 0; c < 4; ++c) {
#pragma unroll
        for (int r = 0; r < 4; ++r) {
            const int row = s0 + quad * 4 + r;
            const int col = t0 + c * 16 + m16;
            attn[((long)(b * 1024 + row)) * 1024 + col] = pm[c][r] * 0.0625f;  // 1/H
        }
    }
}

// ---------------------------------------------------------------------------
extern "C" void kernel_launch(void* const* d_in, const int* in_sizes, int n_in,
                              void* d_out, int out_size, void* d_ws, size_t ws_size,
                              hipStream_t stream)
{
    const float* queries = (const float*)d_in[0];   // [4,1024,1024]
    const float* keys    = (const float*)d_in[1];
    const float* values  = (const float*)d_in[2];
    // d_in[3] = tril mask: causality hardcoded
    const float* Wq = (const float*)d_in[4];        // [16,1024,64]
    const float* bq = (const float*)d_in[5];        // [16,64] == bias[n]
    const float* Wk = (const float*)d_in[6];
    const float* bk = (const float*)d_in[7];
    const float* Wv = (const float*)d_in[8];        // [1024,64]
    const float* bv = (const float*)d_in[9];        // [64]
    const float* Wo = (const float*)d_in[10];       // [64,1024]
    const float* bo = (const float*)d_in[11];       // [1024]

    float* out_ptr  = (float*)d_out;                   // [4096][1024]
    float* attn_ptr = out_ptr + (long)4096 * 1024;     // [4][1024][1024]

    uint8_t* w = (uint8_t*)d_ws;
    size_t off = 0;
    auto alloc = [&](size_t bytes) {
        void* p = w + off;
        off = (off + bytes + 255) & ~(size_t)255;
        return p;
    };
    _Float16* WqT  = (_Float16*)alloc((size_t)1024 * 1024 * 2);  // [n=h*64+e][d]
    _Float16* WkT  = (_Float16*)alloc((size_t)1024 * 1024 * 2);
    _Float16* WvT  = (_Float16*)alloc((size_t)64 * 1024 * 2);    // [e][d]
    _Float16* WoT  = (_Float16*)alloc((size_t)1024 * 64 * 2);    // [d][e]
    _Float16* qall = (_Float16*)alloc((size_t)4096 * 1024 * 2);  // fp16 [B*S][H*HS]
    _Float16* kall = (_Float16*)alloc((size_t)4096 * 1024 * 2);
    float*    vbuf = (float*)alloc((size_t)4096 * 64 * 4);       // [B*S][64] fp32
    _Float16* vT   = (_Float16*)alloc((size_t)4 * 64 * 1024 * 2);// per-b [e][t]
    float*    ctx  = (float*)alloc((size_t)4096 * 64 * 4);
    float*    mbuf = (float*)alloc((size_t)65536 * 4);           // [B,H,S]
    float*    ilbuf= (float*)alloc((size_t)65536 * 4);
    (void)ws_size; (void)in_sizes; (void)n_in; (void)out_size;

    // weight transposes/conversions
    transpose_to_f16<<<dim3(2, 32, 16), 256, 0, stream>>>(Wq, WqT, 1024, 64, 65536, 65536);
    transpose_to_f16<<<dim3(2, 32, 16), 256, 0, stream>>>(Wk, WkT, 1024, 64, 65536, 65536);
    transpose_to_f16<<<dim3(2, 32, 1),  256, 0, stream>>>(Wv, WvT, 1024, 64, 0, 0);
    transpose_to_f16<<<dim3(32, 2, 1),  256, 0, stream>>>(Wo, WoT, 64, 1024, 0, 0);

    // projections: q_all/k_all fp16, v fp32
    gemm_f16<<<dim3(8, 32, 1), 256, 0, stream>>>(queries, WqT, bq, qall,
        4096, 1024, 1024, 1024, 1024, 1024, 0, 0, 0, 1);
    gemm_f16<<<dim3(8, 32, 1), 256, 0, stream>>>(keys, WkT, bk, kall,
        4096, 1024, 1024, 1024, 1024, 1024, 0, 0, 0, 1);
    gemm_f16<<<dim3(1, 32, 1), 256, 0, stream>>>(values, WvT, bv, vbuf,
        4096, 64, 1024, 1024, 1024, 64, 0, 0, 0, 0);

    // vT per batch: [1024][64] -> [64][1024] fp16
    transpose_to_f16<<<dim3(2, 32, 4), 256, 0, stream>>>(vbuf, vT, 1024, 64, 65536, 65536);

    // softmax stats then head-averaged probabilities (writes full attn incl. zeros)
    attn_stats<<<dim3(16, 16, 4), 256, 0, stream>>>(qall, kall, mbuf, ilbuf);
    attn_pmean<<<dim3(16, 16, 4), 256, 0, stream>>>(qall, kall, mbuf, ilbuf, attn_ptr);

    // ctx[b] = attn_mean[b] @ v[b]   (A fp32 read back from d_out)
    gemm_f16<<<dim3(1, 8, 4), 256, 0, stream>>>(attn_ptr, vT, nullptr, ctx,
        1024, 64, 1024, 1024, 1024, 64,
        (long)1024 * 1024, (long)64 * 1024, (long)1024 * 64, 0);
    // out = ctx @ Wo + bo
    gemm_f16<<<dim3(8, 32, 1), 256, 0, stream>>>(ctx, WoT, bo, out_ptr,
        4096, 1024, 64, 64, 64, 1024, 0, 0, 0, 0);
}

// Round 9
// 348.643 us; speedup vs baseline: 2.2052x; 1.6563x over previous
//
#include <hip/hip_runtime.h>
#include <hip/hip_bf16.h>
#include <stdint.h>

typedef _Float16 half8 __attribute__((ext_vector_type(8)));
typedef _Float16 half4 __attribute__((ext_vector_type(4)));
typedef float    f32x4 __attribute__((ext_vector_type(4)));

#define MFMA16(a, b, c) __builtin_amdgcn_mfma_f32_16x16x32_f16(a, b, c, 0, 0, 0)

// ---------------------------------------------------------------------------
// Generic fp32->fp16 transpose: X [R][C] fp32 -> Y [C][R] fp16, z-batched.
// ---------------------------------------------------------------------------
__global__ __launch_bounds__(256) void transpose_to_f16(
    const float* __restrict__ X, _Float16* __restrict__ Y,
    int R, int C, long inBS, long outBS)
{
    __shared__ float t[32][33];
    const int bz = blockIdx.z;
    X += (long)bz * inBS;
    Y += (long)bz * outBS;
    const int c0 = blockIdx.x * 32, r0 = blockIdx.y * 32;
    const int tx = threadIdx.x & 31, ty = threadIdx.x >> 5;
#pragma unroll
    for (int i = 0; i < 4; ++i)
        t[ty + i * 8][tx] = X[(long)(r0 + ty + i * 8) * C + c0 + tx];
    __syncthreads();
#pragma unroll
    for (int i = 0; i < 4; ++i)
        Y[(long)(c0 + ty + i * 8) * R + r0 + tx] = (_Float16)t[tx][ty + i * 8];
}

// ---------------------------------------------------------------------------
// MFMA GEMM v2: C[M,N] = A[M,K](fp32) @ BT[N,K](fp16). R5-passing structure
// (register staging) with three fixes:
//  * staging loads BATCHED into named registers (8 loads in flight, 1 wait)
//    -- R5 evidence: serial load->cvt->ds_write chains cost 14k cyc/K-iter.
//  * dual-input fusion: when A1 != null, z (=b) in {0,1} selects A0/A1 +
//    bias0/bias1 + BT/C offsets (q and k projections in ONE dispatch).
//  * split-K (nks chunks of kchunk) with fp32 atomicAdd epilogue for N=64
//    GEMMs (caller zeroes C); bias added only by the ks==0 splits.
// z = b*nks + ks. M from grid. N may be < 128 (store-guarded).
// ---------------------------------------------------------------------------
__global__ __launch_bounds__(256, 2) void gemm_f16_v2(
    const float* __restrict__ A0, const float* __restrict__ A1,
    const _Float16* __restrict__ BT,
    const float* __restrict__ bias0, const float* __restrict__ bias1,
    void* __restrict__ Cout,
    int N, int lda, int ldbt, int ldc,
    long aBS, long bBS, long cBS,
    int c_half, int atomic, int nks, int kchunk)
{
    __shared__ __align__(16) _Float16 As[128][72];
    __shared__ __align__(16) _Float16 Bs[128][72];

    const int nt = blockIdx.x, mt = blockIdx.y;
    const int b = blockIdx.z / nks, ks = blockIdx.z % nks;
    const int kbeg = ks * kchunk;

    const float* A = A1 ? (b ? A1 : A0) : (A0 + (long)b * aBS);
    const _Float16* Bb = BT + (long)b * bBS;

    const int n0 = nt * 128;
    const int m0 = mt * 128;
    const int tid  = threadIdx.x;
    const int wave = tid >> 6, lane = tid & 63;
    const int m16  = lane & 15, quad = lane >> 4;

    f32x4 acc[2][8];
    {
        f32x4 z = {0.f, 0.f, 0.f, 0.f};
#pragma unroll
        for (int i = 0; i < 2; ++i)
#pragma unroll
            for (int j = 0; j < 8; ++j) acc[i][j] = z;
    }

    for (int k0 = kbeg; k0 < kbeg + kchunk; k0 += 64) {
        // ---- stage A tile: batch 8 loads, then convert+write
        {
            const int cc = (tid & 15) * 4;
            const int rb = tid >> 4;
            float4 av[8];
#pragma unroll
            for (int p = 0; p < 8; ++p)
                av[p] = *(const float4*)(A + (long)(m0 + rb + p * 16) * lda + k0 + cc);
#pragma unroll
            for (int p = 0; p < 8; ++p) {
                half4 hv;
                hv[0] = (_Float16)av[p].x; hv[1] = (_Float16)av[p].y;
                hv[2] = (_Float16)av[p].z; hv[3] = (_Float16)av[p].w;
                *(half4*)&As[rb + p * 16][cc] = hv;
            }
        }
        // ---- stage B tile: batch 4 loads, then write
        {
            const int j  = tid >> 1;
            const int cc = (tid & 1) * 32;
            int jn = n0 + j; if (jn > N - 1) jn = N - 1;
            const _Float16* bp = Bb + (long)jn * ldbt + k0 + cc;
            half8 b0 = *(const half8*)(bp);
            half8 b1 = *(const half8*)(bp + 8);
            half8 b2 = *(const half8*)(bp + 16);
            half8 b3 = *(const half8*)(bp + 24);
            *(half8*)&Bs[j][cc]      = b0;
            *(half8*)&Bs[j][cc + 8]  = b1;
            *(half8*)&Bs[j][cc + 16] = b2;
            *(half8*)&Bs[j][cc + 24] = b3;
        }
        __syncthreads();
#pragma unroll
        for (int kss = 0; kss < 2; ++kss) {
            const int ko = kss * 32 + quad * 8;
            const half8 a0 = *(const half8*)&As[wave * 32 + m16][ko];
            const half8 a1 = *(const half8*)&As[wave * 32 + 16 + m16][ko];
#pragma unroll
            for (int c = 0; c < 8; ++c) {
                const half8 bf = *(const half8*)&Bs[c * 16 + m16][ko];
                acc[0][c] = MFMA16(a0, bf, acc[0][c]);
                acc[1][c] = MFMA16(a1, bf, acc[1][c]);
            }
        }
        __syncthreads();
    }

    // ---- epilogue: C/D layout col=lane&15, row=quad*4+r
    const float* bias = b ? bias1 : bias0;
    const int addb = (bias != nullptr) && (kbeg == 0);
#pragma unroll
    for (int hh = 0; hh < 2; ++hh) {
#pragma unroll
        for (int c = 0; c < 8; ++c) {
            const int col = n0 + c * 16 + m16;
            if (col >= N) continue;
            const float bb = addb ? bias[col] : 0.f;
#pragma unroll
            for (int r = 0; r < 4; ++r) {
                const int row = m0 + wave * 32 + hh * 16 + quad * 4 + r;
                const float v = acc[hh][c][r] + bb;
                const long idx = (long)b * cBS + (long)row * ldc + col;
                if (atomic)      atomicAdd(&((float*)Cout)[idx], v);
                else if (c_half) ((_Float16*)Cout)[idx] = (_Float16)v;
                else             ((float*)Cout)[idx] = v;
            }
        }
    }
}

// ---------------------------------------------------------------------------
// Pass 1: per (b,h,s) row stats m, l for causal softmax.  (unchanged, R5-pass)
// ---------------------------------------------------------------------------
__global__ __launch_bounds__(256) void attn_stats(
    const _Float16* __restrict__ q_all, const _Float16* __restrict__ k_all,
    float* __restrict__ m_out, float* __restrict__ il_out)
{
    const int st = blockIdx.x, h = blockIdx.y, b = blockIdx.z;
    const int tid = threadIdx.x, wave = tid >> 6, lane = tid & 63;
    const int m16 = lane & 15, quad = lane >> 4;
    const int s0 = st * 64 + wave * 16;

    const _Float16* qp = q_all + ((long)(b * 1024 + s0 + m16)) * 1024 + h * 64 + quad * 8;
    const half8 a0 = *(const half8*)qp;
    const half8 a1 = *(const half8*)(qp + 32);

    float mr[4], lr[4];
#pragma unroll
    for (int r = 0; r < 4; ++r) { mr[r] = -3.0e38f; lr[r] = 0.f; }

    const int ntiles = st * 4 + 4;
    const _Float16* kb = k_all + ((long)(b * 1024 + m16)) * 1024 + h * 64 + quad * 8;
    for (int tt = 0; tt < ntiles; ++tt) {
        const _Float16* kp = kb + (long)tt * 16 * 1024;
        const half8 b0 = *(const half8*)kp;
        const half8 b1 = *(const half8*)(kp + 32);
        f32x4 c = {0.f, 0.f, 0.f, 0.f};
        c = MFMA16(a0, b0, c);
        c = MFMA16(a1, b1, c);
        const int col = tt * 16 + m16;
#pragma unroll
        for (int r = 0; r < 4; ++r) {
            const int row = s0 + quad * 4 + r;
            if (col <= row) {
                const float z  = c[r] * 0.125f;
                const float nm = fmaxf(mr[r], z);
                lr[r] = lr[r] * __expf(mr[r] - nm) + __expf(z - nm);
                mr[r] = nm;
            }
        }
    }
#pragma unroll
    for (int mk = 1; mk < 16; mk <<= 1) {
#pragma unroll
        for (int r = 0; r < 4; ++r) {
            const float om = __shfl_xor(mr[r], mk);
            const float ol = __shfl_xor(lr[r], mk);
            const float nm = fmaxf(mr[r], om);
            lr[r] = lr[r] * __expf(mr[r] - nm) + ol * __expf(om - nm);
            mr[r] = nm;
        }
    }
    if (m16 == 0) {
#pragma unroll
        for (int r = 0; r < 4; ++r) {
            const long idx = ((long)(b * 16 + h)) * 1024 + s0 + quad * 4 + r;
            m_out[idx]  = mr[r];
            il_out[idx] = 1.f / lr[r];
        }
    }
}

// ---------------------------------------------------------------------------
// Pass 2: attn_mean = (1/H) sum_h softmax. Upper-triangle tiles zero-fill.
// (unchanged, R5-pass)
// ---------------------------------------------------------------------------
__global__ __launch_bounds__(256) void attn_pmean(
    const _Float16* __restrict__ q_all, const _Float16* __restrict__ k_all,
    const float* __restrict__ m_in, const float* __restrict__ il_in,
    float* __restrict__ attn)
{
    const int ttile = blockIdx.x, stile = blockIdx.y, b = blockIdx.z;
    const int tid = threadIdx.x;
    if (ttile > stile) {
        const int c4 = (tid & 15) * 4;
        float4 z = {0.f, 0.f, 0.f, 0.f};
#pragma unroll
        for (int i = 0; i < 4; ++i) {
            const int r = stile * 64 + (tid >> 4) + i * 16;
            *(float4*)&attn[((long)(b * 1024 + r)) * 1024 + ttile * 64 + c4] = z;
        }
        return;
    }
    const int wave = tid >> 6, lane = tid & 63;
    const int m16 = lane & 15, quad = lane >> 4;
    const int s0 = stile * 64 + wave * 16;
    const int t0 = ttile * 64;

    float pm[4][4];
#pragma unroll
    for (int c = 0; c < 4; ++c)
#pragma unroll
        for (int r = 0; r < 4; ++r) pm[c][r] = 0.f;

    for (int h = 0; h < 16; ++h) {
        const _Float16* qp = q_all + ((long)(b * 1024 + s0 + m16)) * 1024 + h * 64 + quad * 8;
        const half8 a0 = *(const half8*)qp;
        const half8 a1 = *(const half8*)(qp + 32);
        float mrow[4], irow[4];
#pragma unroll
        for (int r = 0; r < 4; ++r) {
            const long idx = ((long)(b * 16 + h)) * 1024 + s0 + quad * 4 + r;
            mrow[r] = m_in[idx];
            irow[r] = il_in[idx];
        }
#pragma unroll
        for (int c = 0; c < 4; ++c) {
            const _Float16* kp = k_all + ((long)(b * 1024 + t0 + c * 16 + m16)) * 1024 + h * 64 + quad * 8;
            const half8 b0 = *(const half8*)kp;
            const half8 b1 = *(const half8*)(kp + 32);
            f32x4 cc = {0.f, 0.f, 0.f, 0.f};
            cc = MFMA16(a0, b0, cc);
            cc = MFMA16(a1, b1, cc);
            const int col = t0 + c * 16 + m16;
#pragma unroll
            for (int r = 0; r < 4; ++r) {
                const int row = s0 + quad * 4 + r;
                if (col <= row)
                    pm[c][r] += __expf(cc[r] * 0.125f - mrow[r]) * irow[r];
            }
        }
    }
#pragma unroll
    for (int c = 0; c < 4; ++c) {
#pragma unroll
        for (int r = 0; r < 4; ++r) {
            const int row = s0 + quad * 4 + r;
            const int col = t0 + c * 16 + m16;
            attn[((long)(b * 1024 + row)) * 1024 + col] = pm[c][r] * 0.0625f;
        }
    }
}

// ---------------------------------------------------------------------------
extern "C" void kernel_launch(void* const* d_in, const int* in_sizes, int n_in,
                              void* d_out, int out_size, void* d_ws, size_t ws_size,
                              hipStream_t stream)
{
    const float* queries = (const float*)d_in[0];
    const float* keys    = (const float*)d_in[1];
    const float* values  = (const float*)d_in[2];
    const float* Wq = (const float*)d_in[4];
    const float* bq = (const float*)d_in[5];
    const float* Wk = (const float*)d_in[6];
    const float* bk = (const float*)d_in[7];
    const float* Wv = (const float*)d_in[8];
    const float* bv = (const float*)d_in[9];
    const float* Wo = (const float*)d_in[10];
    const float* bo = (const float*)d_in[11];

    float* out_ptr  = (float*)d_out;                   // [4096][1024]
    float* attn_ptr = out_ptr + (long)4096 * 1024;     // [4][1024][1024]

    uint8_t* w = (uint8_t*)d_ws;
    size_t off = 0;
    auto alloc = [&](size_t bytes) {
        void* p = w + off;
        off = (off + bytes + 255) & ~(size_t)255;
        return p;
    };
    _Float16* WqkT  = (_Float16*)alloc((size_t)2 * 1024 * 1024 * 2); // WqT|WkT [n][d]
    _Float16* WvT   = (_Float16*)alloc((size_t)64 * 1024 * 2);       // [e][d]
    _Float16* WoT   = (_Float16*)alloc((size_t)1024 * 64 * 2);       // [d][e]
    _Float16* qkall = (_Float16*)alloc((size_t)2 * 4194304 * 2);     // qall|kall
    float*    vbuf  = (float*)alloc((size_t)4096 * 64 * 4);
    _Float16* vT    = (_Float16*)alloc((size_t)4 * 64 * 1024 * 2);   // per-b [e][t]
    float*    ctx   = (float*)alloc((size_t)4096 * 64 * 4);
    float*    mbuf  = (float*)alloc((size_t)65536 * 4);
    float*    ilbuf = (float*)alloc((size_t)65536 * 4);
    (void)ws_size; (void)in_sizes; (void)n_in; (void)out_size;

    _Float16* qall = qkall;
    _Float16* kall = qkall + (long)4194304;

    // weight transposes/conversions
    transpose_to_f16<<<dim3(2, 32, 16), 256, 0, stream>>>(Wq, WqkT, 1024, 64, 65536, 65536);
    transpose_to_f16<<<dim3(2, 32, 16), 256, 0, stream>>>(Wk, WqkT + (long)1024 * 1024, 1024, 64, 65536, 65536);
    transpose_to_f16<<<dim3(2, 32, 1),  256, 0, stream>>>(Wv, WvT, 1024, 64, 0, 0);
    transpose_to_f16<<<dim3(32, 2, 1),  256, 0, stream>>>(Wo, WoT, 64, 1024, 0, 0);

    // fused q+k projection: z selects queries/Wq/bq vs keys/Wk/bk; 512 blocks
    gemm_f16_v2<<<dim3(8, 32, 2), 256, 0, stream>>>(
        queries, keys, WqkT, bq, bk, qkall,
        1024, 1024, 1024, 1024,
        0, (long)1048576, (long)4194304,
        /*c_half=*/1, /*atomic=*/0, /*nks=*/1, /*kchunk=*/1024);

    // v projection: split-K x8 atomic into vbuf (zeroed) -> 256 blocks
    hipMemsetAsync(vbuf, 0, (size_t)4096 * 64 * 4, stream);
    gemm_f16_v2<<<dim3(1, 32, 8), 256, 0, stream>>>(
        values, nullptr, WvT, bv, nullptr, vbuf,
        64, 1024, 1024, 64,
        0, 0, 0,
        /*c_half=*/0, /*atomic=*/1, /*nks=*/8, /*kchunk=*/128);

    // vT per batch: [1024][64] -> [64][1024] fp16
    transpose_to_f16<<<dim3(2, 32, 4), 256, 0, stream>>>(vbuf, vT, 1024, 64, 65536, 65536);

    // softmax stats then head-averaged probabilities (writes full attn)
    attn_stats<<<dim3(16, 16, 4), 256, 0, stream>>>(qall, kall, mbuf, ilbuf);
    attn_pmean<<<dim3(16, 16, 4), 256, 0, stream>>>(qall, kall, mbuf, ilbuf, attn_ptr);

    // ctx[b] = attn_mean[b] @ v[b]: batch x split-K x8 atomic -> 256 blocks
    hipMemsetAsync(ctx, 0, (size_t)4096 * 64 * 4, stream);
    gemm_f16_v2<<<dim3(1, 8, 32), 256, 0, stream>>>(
        attn_ptr, nullptr, vT, nullptr, nullptr, ctx,
        64, 1024, 1024, 64,
        (long)1048576, (long)65536, (long)65536,
        /*c_half=*/0, /*atomic=*/1, /*nks=*/8, /*kchunk=*/128);

    // out = ctx @ Wo + bo (K=64: single iteration)
    gemm_f16_v2<<<dim3(8, 32, 1), 256, 0, stream>>>(
        ctx, nullptr, WoT, bo, nullptr, out_ptr,
        1024, 64, 64, 1024,
        0, 0, 0,
        /*c_half=*/0, /*atomic=*/0, /*nks=*/1, /*kchunk=*/64);
}